// Round 8
// baseline (262.026 us; speedup 1.0000x reference)
//
#include <hip/hip_runtime.h>
#include <stdint.h>

// ---------------------------------------------------------------------------
// QuantBertSelfOutput: out = LayerNorm( hs @ fakequant(W)^T + b + residual )
// Round 8 (resubmit of round 7 — GPU acquisition timeout, no signal):
// BM=32, 512-thread blocks, grid=512 -> TWO blocks per CU so the three phases
// (HBM stage / L2-bound K-loop / HBM epilogue) overlap across resident
// blocks. acc[2][8]=64 regs keeps total <=128 under __launch_bounds__(512,4).
// Full 64KB A-tile staged once (conflict-free); barrier-free K-loop;
// transposed mfma (D[oc][m]) -> float4 epilogue.
// fp16 single-MFMA path (q integers exact in fp16; passed at absmax 0.031).
// ---------------------------------------------------------------------------

#define D_DIM 1024
#define BM 32
#define LDS_BYTES 65536               // 64 frags x 1KB: full 32x1024 fp16 tile

typedef float f32x4 __attribute__((ext_vector_type(4)));
typedef _Float16 f16x8 __attribute__((ext_vector_type(8)));   // 8 x fp16

// ---------------- prepass: fake-quant W -> fp16 fragment layout -------------
// qf 16B-chunk index for (col c, k): (s*64 + (c>>4))*64 + l4*16 + (c&15),
// s=k>>5, l4=(k>>3)&3. A wave's frag (s, colgroup) = 64 lanes x 16B contiguous.
__global__ __launch_bounds__(256) void quantw_kernel(
    const float* __restrict__ W, uint16_t* __restrict__ qf,
    float* __restrict__ scale) {
  const int c = blockIdx.x;        // output channel (row of W)
  const int t = threadIdx.x;
  __shared__ float redmax[4];
  __shared__ __align__(16) uint16_t qrow[D_DIM];

  float4 w4 = reinterpret_cast<const float4*>(W + (size_t)c * D_DIM)[t];
  float am = fmaxf(fmaxf(fabsf(w4.x), fabsf(w4.y)),
                   fmaxf(fabsf(w4.z), fabsf(w4.w)));
#pragma unroll
  for (int d = 1; d < 64; d <<= 1) am = fmaxf(am, __shfl_xor(am, d));
  if ((t & 63) == 0) redmax[t >> 6] = am;
  __syncthreads();
  am = fmaxf(fmaxf(redmax[0], redmax[1]), fmaxf(redmax[2], redmax[3]));
  float sc = fmaxf(am / 127.0f, 1e-8f);
  if (t == 0) scale[c] = sc;

  float v[4] = {w4.x, w4.y, w4.z, w4.w};
#pragma unroll
  for (int i = 0; i < 4; ++i) {
    float qq = fminf(fmaxf(rintf(v[i] / sc), -128.0f), 127.0f);
    union { _Float16 h; uint16_t u; } cv;
    cv.h = (_Float16)qq;             // integer in [-128,127]: exact in fp16
    qrow[4 * t + i] = cv.u;
  }
  __syncthreads();
  if (t < 128) {                     // 16B chunk t covers k = 8t..8t+7
    int s = t >> 2, l4 = t & 3;
    size_t off16 = (size_t)(s * 64 + (c >> 4)) * 64 + l4 * 16 + (c & 15);
    reinterpret_cast<float4*>(qf)[off16] =
        reinterpret_cast<const float4*>(qrow)[t];
  }
}

__device__ __forceinline__ f16x8 cvt8(f32x4 x0, f32x4 x1) {
  f16x8 r;
  r[0] = (_Float16)x0.x; r[1] = (_Float16)x0.y;
  r[2] = (_Float16)x0.z; r[3] = (_Float16)x0.w;
  r[4] = (_Float16)x1.x; r[5] = (_Float16)x1.y;
  r[6] = (_Float16)x1.z; r[7] = (_Float16)x1.w;
  return r;
}

// ---------------- fused GEMM (fp16) + bias + residual + LayerNorm -----------
__global__ __launch_bounds__(512, 4) void gemm_ln_kernel(
    const float* __restrict__ hs, const float* __restrict__ res,
    const uint16_t* __restrict__ qf, const float* __restrict__ scale,
    const float* __restrict__ bias, const float* __restrict__ lnw,
    const float* __restrict__ lnb, float* __restrict__ out) {
  extern __shared__ char lds[];      // 64KB A tile, frag f at f*1024+lane*16
  const int tid  = threadIdx.x;
  const int lane = tid & 63;
  const int w    = tid >> 6;         // wave 0..7, owns oc w*128..w*128+127
  const int l15  = lane & 15;
  const int l4   = lane >> 4;
  const size_t brow = (size_t)blockIdx.x * BM;

  // ---- phase 1: stage full 32x1024 tile fp32->fp16 (each wave: 8 frags;
  //      LDS writes wave-contiguous 1KB -> conflict-free; 16 loads in flight)
#pragma unroll
  for (int i = 0; i < 8; ++i) {
    const int f  = w * 8 + i;        // frag id = mf*32 + s
    const int mf = f >> 5, s = f & 31;
    const float* ap = hs + (brow + mf * 16 + l15) * D_DIM + s * 32 + l4 * 8;
    f32x4 x0 = *reinterpret_cast<const f32x4*>(ap);
    f32x4 x1 = *reinterpret_cast<const f32x4*>(ap + 4);
    *reinterpret_cast<f16x8*>(lds + f * 1024 + lane * 16) = cvt8(x0, x1);
  }
  __syncthreads();                   // the only pre-epilogue barrier

  // ---- phase 2: barrier-free K-loop (q from L2, hs from LDS) ----
  f32x4 acc[2][8] = {};              // D[oc][m]: 64 regs
  const uint16_t* qBase = qf + ((size_t)(w * 8) * 64 + lane) * 8;
  const int laneOff = lane * 16;

#pragma unroll 2
  for (int s = 0; s < 32; ++s) {
    f16x8 qa[8], hb[2];
#pragma unroll
    for (int nf = 0; nf < 8; ++nf)   // 1KB/wave contiguous L2 reads
      qa[nf] = *reinterpret_cast<const f16x8*>(
          qBase + ((size_t)s * 4096 + (size_t)nf * 64) * 8);
#pragma unroll
    for (int mf = 0; mf < 2; ++mf)   // conflict-free ds_read_b128
      hb[mf] = *reinterpret_cast<const f16x8*>(
          lds + (mf * 32 + s) * 1024 + laneOff);
#pragma unroll
    for (int mf = 0; mf < 2; ++mf)
#pragma unroll
      for (int nf = 0; nf < 8; ++nf) // D[oc][m]
        acc[mf][nf] = __builtin_amdgcn_mfma_f32_16x16x32_f16(
            qa[nf], hb[mf], acc[mf][nf], 0, 0, 0);
  }

  // ---- phase 3: z = acc*scale + bias + res; LN over oc; float4 I/O ----
  // D layout (verified r6): m = mf*16 + l15, oc = w*128 + nf*16 + l4*4 + r.
  float* redsum = reinterpret_cast<float*>(lds);           // [8][32]
  float* redsq  = redsum + 256;                            // [8][32]
  float2* stats = reinterpret_cast<float2*>(lds + 2048);   // [32]

  const int ocb0 = w * 128 + l4 * 4;
  float sums[2], sqs[2];
#pragma unroll
  for (int mf = 0; mf < 2; ++mf) {
    const size_t rowoff = (brow + mf * 16 + l15) * D_DIM;
    float sum = 0.f, sq = 0.f;
#pragma unroll
    for (int nf = 0; nf < 8; ++nf) {
      const int ocb = ocb0 + nf * 16;
      f32x4 scl4 = *reinterpret_cast<const f32x4*>(scale + ocb);
      f32x4 bs4  = *reinterpret_cast<const f32x4*>(bias + ocb);
      f32x4 rs4  = *reinterpret_cast<const f32x4*>(res + rowoff + ocb);
      f32x4 z;
#pragma unroll
      for (int r = 0; r < 4; ++r) {
        z[r] = acc[mf][nf][r] * scl4[r] + bs4[r] + rs4[r];
        sum += z[r];
        sq  += z[r] * z[r];
      }
      acc[mf][nf] = z;               // keep z for the normalize pass
    }
    sums[mf] = sum; sqs[mf] = sq;
  }
  __syncthreads();                   // A tile dead; LDS now reduction scratch
#pragma unroll
  for (int mf = 0; mf < 2; ++mf) {
    float sum = sums[mf], sq = sqs[mf];
    sum += __shfl_xor(sum, 16); sq += __shfl_xor(sq, 16);
    sum += __shfl_xor(sum, 32); sq += __shfl_xor(sq, 32);
    if (l4 == 0) {                   // one partial per (wave, row)
      redsum[w * 32 + mf * 16 + l15] = sum;
      redsq [w * 32 + mf * 16 + l15] = sq;
    }
  }
  __syncthreads();
  if (tid < 32) {                    // combine 8 waves' partials per row
    float s = 0.f, ss = 0.f;
#pragma unroll
    for (int ww = 0; ww < 8; ++ww) {
      s  += redsum[ww * 32 + tid];
      ss += redsq [ww * 32 + tid];
    }
    float mu  = s * (1.0f / 1024.0f);
    float var = ss * (1.0f / 1024.0f) - mu * mu;
    stats[tid] = make_float2(mu, 1.0f / sqrtf(var + 1e-12f));
  }
  __syncthreads();

#pragma unroll
  for (int mf = 0; mf < 2; ++mf) {
    const float2 st = stats[mf * 16 + l15];
    const size_t rowoff = (brow + mf * 16 + l15) * D_DIM;
#pragma unroll
    for (int nf = 0; nf < 8; ++nf) {
      const int ocb = ocb0 + nf * 16;
      f32x4 lw4 = *reinterpret_cast<const f32x4*>(lnw + ocb);
      f32x4 lb4 = *reinterpret_cast<const f32x4*>(lnb + ocb);
      f32x4 o;
#pragma unroll
      for (int r = 0; r < 4; ++r)
        o[r] = (acc[mf][nf][r] - st.x) * st.y * lw4[r] + lb4[r];
      *reinterpret_cast<f32x4*>(out + rowoff + ocb) = o;   // float4 store
    }
  }
}

// ---------------------------------------------------------------------------
extern "C" void kernel_launch(void* const* d_in, const int* in_sizes, int n_in,
                              void* d_out, int out_size, void* d_ws, size_t ws_size,
                              hipStream_t stream) {
  const float* hs  = (const float*)d_in[0];   // [M,1024] fp32
  const float* res = (const float*)d_in[1];   // [M,1024] fp32
  const float* W   = (const float*)d_in[2];   // [1024,1024] fp32
  const float* b   = (const float*)d_in[3];
  const float* lnw = (const float*)d_in[4];
  const float* lnb = (const float*)d_in[5];
  float* out = (float*)d_out;

  // workspace: scale[1024] fp32 @0, qf fp16 fragment-swizzled @4096 (2 MiB)
  float*    scale = (float*)d_ws;
  uint16_t* qf    = (uint16_t*)((char*)d_ws + 4096);

  const int M = in_sizes[0] / D_DIM;          // 16384

  hipFuncSetAttribute((const void*)gemm_ln_kernel,
                      hipFuncAttributeMaxDynamicSharedMemorySize, LDS_BYTES);

  quantw_kernel<<<dim3(D_DIM), dim3(256), 0, stream>>>(W, qf, scale);
  gemm_ln_kernel<<<dim3(M / BM), dim3(512), LDS_BYTES, stream>>>(
      hs, res, qf, scale, b, lnw, lnb, out);
}